// Round 7
// baseline (3601.888 us; speedup 1.0000x reference)
//
#include <hip/hip_runtime.h>
#include <math.h>

#define Tt 4096
#define NB 16

#define CLN2PI 1.8378770664093453f   // ln(2*pi)

// ws layout (float offsets)
#define OFF_W    0         // 131072  W = L^-1 per state (row-major, upper zeros)
#define OFF_D    131072    // 2048    d = W*mu
#define OFF_CST  133120    // 32      F*ln2pi + logdet  (nats)
#define OFF_EV   133152    // 16      evidence per batch (fp32 nats)
#define OFF_LB   133184    // 2097152 logB nats [b][t][s]
#define OFF_BET  2230336   // 2097152 beta  nats [b][t][s]
// total 4327488 floats = 17.3 MB

__device__ __forceinline__ float rdlane(float x, int l) {
  return __int_as_float(__builtin_amdgcn_readlane(__float_as_int(x), l));
}

// Per-lane cross-half exchange via v_permlane32_swap (VALU, ~10cy).
// With old=src=v the swap returns: lo = v[lane&31] (lower partner, same j),
// hi = v[32|(lane&31)] (upper partner, same j) — in ALL lanes. fmax/add of
// (lo,hi) is per-j-correct and bit-identical across halves.
// R4 lesson: inline asm w/ two identical tied operands coalesces -> garbage.
// R5 lesson: rdlane(x, fixed_lane) only valid for wave-uniform x.
typedef unsigned int u32x2 __attribute__((ext_vector_type(2)));
__device__ __forceinline__ void xhalf(float v, float& lo, float& hi) {
  u32x2 r = __builtin_amdgcn_permlane32_swap(__float_as_uint(v), __float_as_uint(v),
                                             false, false);
  lo = __uint_as_float(r.x);
  hi = __uint_as_float(r.y);
}

// ---------------- K2: per-state Cholesky, W = L^-1, d = W*mu, cst ----------------
__global__ __launch_bounds__(64) void k_chol(const float* __restrict__ covs,
                                             const float* __restrict__ means,
                                             float* __restrict__ ws) {
  __shared__ float Am[64][65];
  __shared__ float Wl[64][65];
  int s = blockIdx.x, j = threadIdx.x;
  for (int r = 0; r < 64; ++r) {
    Am[r][j] = covs[((size_t)s * 64 + r) * 64 + j];
    Wl[r][j] = 0.f;
  }
  __syncthreads();
  for (int k = 0; k < 64; ++k) {
    float diag = sqrtf(Am[k][k]);
    float col = (j > k) ? Am[j][k] / diag : 0.f;
    __syncthreads();
    if (j == k) Am[k][k] = diag;
    if (j > k)  Am[j][k] = col;
    __syncthreads();
    if (j > k) {
      for (int g = k + 1; g <= j; ++g) Am[j][g] -= col * Am[g][k];
    }
    __syncthreads();
  }
  {
    int c = j;
    Wl[c][c] = 1.0f / Am[c][c];
    for (int f = c + 1; f < 64; ++f) {
      float ssum = 0.f;
      for (int g = c; g < f; ++g) ssum += Am[f][g] * Wl[g][c];
      Wl[f][c] = -ssum / Am[f][f];
    }
  }
  __syncthreads();
  for (int r = 0; r < 64; ++r)
    ws[OFF_W + ((size_t)s * 64 + r) * 64 + j] = Wl[r][j];
  {
    float acc = 0.f;
    for (int g = 0; g < 64; ++g) acc += Wl[j][g] * means[s * 64 + g];
    ws[OFF_D + s * 64 + j] = acc;
  }
  if (j == 0) {
    float logdet = 0.f;
    for (int k = 0; k < 64; ++k) logdet += __logf(Am[k][k]);
    logdet *= 2.0f;
    ws[OFF_CST + s] = 64.0f * CLN2PI + logdet;
  }
}

// ---------------- K3: emission logB (nats) ----------------
__global__ __launch_bounds__(64) void k_emis(const float* __restrict__ x,
                                             const float* __restrict__ wsr,
                                             float* __restrict__ lb) {
  const float* W = wsr + OFF_W;
  const float* D = wsr + OFF_D;
  const float* C = wsr + OFF_CST;
  int bx = blockIdx.x;
  int sgrp = bx & 3;
  int pt = (bx >> 2) * 64 + threadIdx.x;
  const float* xr = x + (size_t)pt * 64;
  float xv[64];
#pragma unroll
  for (int c = 0; c < 16; ++c) {
    float4 q = ((const float4*)xr)[c];
    xv[4 * c + 0] = q.x; xv[4 * c + 1] = q.y;
    xv[4 * c + 2] = q.z; xv[4 * c + 3] = q.w;
  }
#pragma unroll 1
  for (int si = 0; si < 8; ++si) {
    int s = sgrp * 8 + si;
    const float* Ws = W + (size_t)s * 4096;
    const float* Ds = D + s * 64;
    float maha = 0.f;
#pragma unroll
    for (int f = 0; f < 64; ++f) {
      float z = -Ds[f];
#pragma unroll
      for (int ch = 0; ch < 4; ++ch) {
        if (ch <= (f >> 4)) {
#pragma unroll
          for (int gg = 0; gg < 16; ++gg) {
            int g = ch * 16 + gg;
            z = fmaf(Ws[f * 64 + g], xv[g], z);
          }
        }
      }
      maha = fmaf(z, z, maha);
    }
    lb[(size_t)pt * 32 + s] = -0.5f * (maha + C[s]);
  }
}

// np-pairwise-order sum of 32 (evidence only)
__device__ __forceinline__ float npsum32(const float* z) {
  float r[8];
#pragma unroll
  for (int k = 0; k < 8; ++k)
    r[k] = ((z[k] + z[k + 8]) + z[k + 16]) + z[k + 24];
  return ((r[0] + r[1]) + (r[2] + r[3])) + ((r[4] + r[5]) + (r[6] + r[7]));
}
// exact max of 32 (order-independent, commutative -> any tree ok)
__device__ __forceinline__ float max32(const float* z) {
  float t16[16];
#pragma unroll
  for (int k = 0; k < 16; ++k) t16[k] = fmaxf(z[k], z[k + 16]);
  float t8[8];
#pragma unroll
  for (int k = 0; k < 8; ++k) t8[k] = fmaxf(t16[k], t16[k + 8]);
  float t4[4];
#pragma unroll
  for (int k = 0; k < 4; ++k) t4[k] = fmaxf(t8[k], t8[k + 4]);
  float t2a = fmaxf(t4[0], t4[2]), t2b = fmaxf(t4[1], t4[3]);
  return fmaxf(t2a, t2b);
}
// exact max of 16 (commutative -> any tree yields THE max, bit-exact)
__device__ __forceinline__ float max16(const float* z) {
  float t8[8];
#pragma unroll
  for (int k = 0; k < 8; ++k) t8[k] = fmaxf(z[k], z[k + 8]);
  float t4[4];
#pragma unroll
  for (int k = 0; k < 4; ++k) t4[k] = fmaxf(t8[k], t8[k + 4]);
  return fmaxf(fmaxf(t4[0], t4[2]), fmaxf(t4[1], t4[3]));
}
// tree sum of 16 (order differs from np pairwise; R6 PROVED safe: absmax
// stayed 0.25. The big-magnitude adds (z, logS+m, +bcur) stay np-ordered —
// that's the R1 failure mechanism and it must not be touched.)
__device__ __forceinline__ float sum16(const float* e) {
  float t8[8];
#pragma unroll
  for (int k = 0; k < 8; ++k) t8[k] = e[k] + e[k + 8];
  float t4[4];
#pragma unroll
  for (int k = 0; k < 4; ++k) t4[k] = t8[k] + t8[k + 4];
  return (t4[0] + t4[2]) + (t4[1] + t4[3]);
}

// ---------------- K4: forward+backward fused, fp32 nats ----------------
// R6 lesson: chain is DEPENDENCY-LATENCY-bound (~20% VALU issue on the active
// CU; ~775 of 1010 cyc/step are stalls between dependent VALU ops). Per-step
// op-shaving can't attack that. R7: put BOTH independent chains (fwd+bwd of
// the same batch) in ONE wave, step bodies adjacent in the loop body — the
// scheduler interleaves them, so one chain's ops issue during the other's
// dependency stalls. Two steps per latency window; worst case (no interleave)
// is flat. Per-chain math is bit-identical to the passing R6 kernel.
// 16 blocks x 1 wave. Half-split per chain: lane (h=lane>>5, j=lane&31) owns
// reduction indices i in [16h,16h+16) for state j -> 16 exps/step/chain.
__global__ __launch_bounds__(64, 1) __attribute__((amdgpu_waves_per_eu(1)))
void k_fb(const float* __restrict__ logA,
          const float* __restrict__ logpi,
          float* __restrict__ ws,
          float* __restrict__ out) {
  const float* lbg = ws + OFF_LB;
  float* bet = ws + OFF_BET;
  float* ev  = ws + OFF_EV;
  int b   = blockIdx.x;                  // 0..15
  int lane = threadIdx.x;
  int j = lane & 31;
  int h = lane >> 5;
  int i0 = h << 4;                       // first reduction index this half owns
  const float* lb = lbg + (size_t)b * Tt * 32;
  float* ao = out + (size_t)b * Tt * 32;
  float* bo = bet + (size_t)b * Tt * 32;

  float acol[16];                        // A[i0+k][j]   (fwd)
  float arow[16];                        // A[j][i0+k]   (bwd)
#pragma unroll
  for (int k = 0; k < 16; ++k) {
    acol[k] = logA[(i0 + k) * 32 + j];
    asm volatile("" : "+v"(acol[k]));
  }
#pragma unroll
  for (int k = 0; k < 16; ++k) {
    arow[k] = logA[j * 32 + i0 + k];
    asm volatile("" : "+v"(arow[k]));
  }

  // ---- fwd init ----
  float aF = logpi[j] + lb[j];           // alpha[0], identical in both halves
  ao[j] = aF;
  float fA = lb[32 + j];
  float fB = lb[64 + j];
  float fC = lb[96 + j];
  // ---- bwd init ----
  bo[(size_t)(Tt - 1) * 32 + j] = 0.f;
  float yB = lb[(size_t)(Tt - 1) * 32 + j] + 0.f;   // logB[T-1] + beta[T-1]
  float gA = lb[(size_t)(Tt - 2) * 32 + j];
  float gB = lb[(size_t)(Tt - 3) * 32 + j];
  float gC = lb[(size_t)(Tt - 4) * 32 + j];

#pragma unroll 1
  for (int n = 1; n < Tt; ++n) {
    int tb = Tt - 1 - n;
    // prefetch rotation (3-deep, both streams)
    float bf = fA; fA = fB; fB = fC;
    if (n + 3 < Tt) fC = lb[(size_t)(n + 3) * 32 + j];
    float bg = gA; gA = gB; gB = gC;
    if (tb >= 3) gC = lb[(size_t)(tb - 3) * 32 + j];

    // ======== fwd step (alpha[n]) ========
    float saF[32];
#pragma unroll
    for (int i = 0; i < 32; ++i) saF[i] = rdlane(aF, i);
    float zF[16];
    if (h == 0) {
#pragma unroll
      for (int k = 0; k < 16; ++k) zF[k] = saF[k] + acol[k];      // a_i + A[i][j]
    } else {
#pragma unroll
      for (int k = 0; k < 16; ++k) zF[k] = saF[16 + k] + acol[k];
    }
    float mhF = max16(zF);
    float mloF, mhiF;
    xhalf(mhF, mloF, mhiF);
    float mF = fmaxf(mloF, mhiF);        // full max_i, same bits all lanes
    float eF[16];
#pragma unroll
    for (int k = 0; k < 16; ++k) eF[k] = __expf(zF[k] - mF);
    float shF = sum16(eF);
    float sloF, shiF;
    xhalf(shF, sloF, shiF);
    float SF = sloF + shiF;
    aF = (__logf(SF) + mF) + bf;         // np-ordered final adds
    ao[(size_t)n * 32 + j] = aF;

    // ======== bwd step (beta[tb]) ========
    float syB[32];
#pragma unroll
    for (int i = 0; i < 32; ++i) syB[i] = rdlane(yB, i);
    float zB[16];
    if (h == 0) {
#pragma unroll
      for (int k = 0; k < 16; ++k) zB[k] = arow[k] + syB[k];      // A[j][i]+y_i
    } else {
#pragma unroll
      for (int k = 0; k < 16; ++k) zB[k] = arow[k] + syB[16 + k];
    }
    float mhB = max16(zB);
    float mloB, mhiB;
    xhalf(mhB, mloB, mhiB);
    float mB = fmaxf(mloB, mhiB);
    float eB[16];
#pragma unroll
    for (int k = 0; k < 16; ++k) eB[k] = __expf(zB[k] - mB);
    float shB = sum16(eB);
    float sloB, shiB;
    xhalf(shB, sloB, shiB);
    float SB = sloB + shiB;
    float bv = __logf(SB) + mB;          // beta[tb][j], same bits both halves
    bo[(size_t)tb * 32 + j] = bv;
    yB = bg + bv;                        // logB[tb] + beta[tb] for next step
  }

  // evidence = logsumexp(alpha[T-1]) — np-exact, identical to baseline
  float z[32];
#pragma unroll
  for (int i = 0; i < 32; ++i) z[i] = rdlane(aF, i);
  float m = max32(z);
#pragma unroll
  for (int i = 0; i < 32; ++i) z[i] = __expf(z[i] - m);
  float S = npsum32(z);
  if (lane == 0) ev[b] = __logf(S) + m;
}

// ---------------- K5: gamma = (alpha + beta) - evidence, fp32 ----------------
__global__ void k_gamma(const float* __restrict__ ws, float* __restrict__ out) {
  size_t idx = (size_t)blockIdx.x * blockDim.x + threadIdx.x;
  if (idx >= (size_t)NB * Tt * 32) return;
  int b = (int)(idx >> 17);            // T*S = 131072
  float a  = out[idx];
  float bb = ws[OFF_BET + idx];
  float e  = ws[OFF_EV + b];
  out[idx] = (a + bb) - e;
}

extern "C" void kernel_launch(void* const* d_in, const int* in_sizes, int n_in,
                              void* d_out, int out_size, void* d_ws, size_t ws_size,
                              hipStream_t stream) {
  const float* x     = (const float*)d_in[0];
  const float* means = (const float*)d_in[1];
  const float* covs  = (const float*)d_in[2];
  const float* logA  = (const float*)d_in[3];
  const float* logpi = (const float*)d_in[4];
  float* ws  = (float*)d_ws;
  float* out = (float*)d_out;

  k_chol<<<dim3(32), dim3(64), 0, stream>>>(covs, means, ws);
  k_emis<<<dim3(4096), dim3(64), 0, stream>>>(x, ws, ws + OFF_LB);
  k_fb<<<dim3(16), dim3(64), 0, stream>>>(logA, logpi, ws, out);
  k_gamma<<<dim3(8192), dim3(256), 0, stream>>>(ws, out);
}

// Round 8
// 2833.551 us; speedup vs baseline: 1.2712x; 1.2712x over previous
//
#include <hip/hip_runtime.h>
#include <math.h>

#define Tt 4096
#define NB 16

#define CLN2PI 1.8378770664093453f   // ln(2*pi)

// ws layout (float offsets)
#define OFF_W    0         // 131072  W = L^-1 per state (row-major, upper zeros)
#define OFF_D    131072    // 2048    d = W*mu
#define OFF_CST  133120    // 32      F*ln2pi + logdet  (nats)
#define OFF_EV   133152    // 16      evidence per batch (fp32 nats)
#define OFF_LB   133184    // 2097152 logB nats [b][t][s]
#define OFF_BET  2230336   // 2097152 beta  nats [b][t][s]
// total 4327488 floats = 17.3 MB

__device__ __forceinline__ float rdlane(float x, int l) {
  return __int_as_float(__builtin_amdgcn_readlane(__float_as_int(x), l));
}

// Per-lane cross-half exchange via v_permlane32_swap (VALU, ~10cy).
// With old=src=v: lo = v[lane&31], hi = v[32|(lane&31)] in ALL lanes.
// R4 lesson: inline-asm w/ two identical tied operands coalesces -> garbage;
// the intrinsic models both results -> safe. R5 lesson: rdlane(x, fixed_lane)
// only valid for wave-uniform x.
typedef unsigned int u32x2 __attribute__((ext_vector_type(2)));
__device__ __forceinline__ void xhalf(float v, float& lo, float& hi) {
  u32x2 r = __builtin_amdgcn_permlane32_swap(__float_as_uint(v), __float_as_uint(v),
                                             false, false);
  lo = __uint_as_float(r.x);
  hi = __uint_as_float(r.y);
}

// ---------------- K2: per-state Cholesky, W = L^-1, d = W*mu, cst ----------------
__global__ __launch_bounds__(64) void k_chol(const float* __restrict__ covs,
                                             const float* __restrict__ means,
                                             float* __restrict__ ws) {
  __shared__ float Am[64][65];
  __shared__ float Wl[64][65];
  int s = blockIdx.x, j = threadIdx.x;
  for (int r = 0; r < 64; ++r) {
    Am[r][j] = covs[((size_t)s * 64 + r) * 64 + j];
    Wl[r][j] = 0.f;
  }
  __syncthreads();
  for (int k = 0; k < 64; ++k) {
    float diag = sqrtf(Am[k][k]);
    float col = (j > k) ? Am[j][k] / diag : 0.f;
    __syncthreads();
    if (j == k) Am[k][k] = diag;
    if (j > k)  Am[j][k] = col;
    __syncthreads();
    if (j > k) {
      for (int g = k + 1; g <= j; ++g) Am[j][g] -= col * Am[g][k];
    }
    __syncthreads();
  }
  {
    int c = j;
    Wl[c][c] = 1.0f / Am[c][c];
    for (int f = c + 1; f < 64; ++f) {
      float ssum = 0.f;
      for (int g = c; g < f; ++g) ssum += Am[f][g] * Wl[g][c];
      Wl[f][c] = -ssum / Am[f][f];
    }
  }
  __syncthreads();
  for (int r = 0; r < 64; ++r)
    ws[OFF_W + ((size_t)s * 64 + r) * 64 + j] = Wl[r][j];
  {
    float acc = 0.f;
    for (int g = 0; g < 64; ++g) acc += Wl[j][g] * means[s * 64 + g];
    ws[OFF_D + s * 64 + j] = acc;
  }
  if (j == 0) {
    float logdet = 0.f;
    for (int k = 0; k < 64; ++k) logdet += __logf(Am[k][k]);
    logdet *= 2.0f;
    ws[OFF_CST + s] = 64.0f * CLN2PI + logdet;
  }
}

// ---------------- K3: emission logB (nats) ----------------
__global__ __launch_bounds__(64) void k_emis(const float* __restrict__ x,
                                             const float* __restrict__ wsr,
                                             float* __restrict__ lb) {
  const float* W = wsr + OFF_W;
  const float* D = wsr + OFF_D;
  const float* C = wsr + OFF_CST;
  int bx = blockIdx.x;
  int sgrp = bx & 3;
  int pt = (bx >> 2) * 64 + threadIdx.x;
  const float* xr = x + (size_t)pt * 64;
  float xv[64];
#pragma unroll
  for (int c = 0; c < 16; ++c) {
    float4 q = ((const float4*)xr)[c];
    xv[4 * c + 0] = q.x; xv[4 * c + 1] = q.y;
    xv[4 * c + 2] = q.z; xv[4 * c + 3] = q.w;
  }
#pragma unroll 1
  for (int si = 0; si < 8; ++si) {
    int s = sgrp * 8 + si;
    const float* Ws = W + (size_t)s * 4096;
    const float* Ds = D + s * 64;
    float maha = 0.f;
#pragma unroll
    for (int f = 0; f < 64; ++f) {
      float z = -Ds[f];
#pragma unroll
      for (int ch = 0; ch < 4; ++ch) {
        if (ch <= (f >> 4)) {
#pragma unroll
          for (int gg = 0; gg < 16; ++gg) {
            int g = ch * 16 + gg;
            z = fmaf(Ws[f * 64 + g], xv[g], z);
          }
        }
      }
      maha = fmaf(z, z, maha);
    }
    lb[(size_t)pt * 32 + s] = -0.5f * (maha + C[s]);
  }
}

// np-pairwise-order sum of 32 (evidence only)
__device__ __forceinline__ float npsum32(const float* z) {
  float r[8];
#pragma unroll
  for (int k = 0; k < 8; ++k)
    r[k] = ((z[k] + z[k + 8]) + z[k + 16]) + z[k + 24];
  return ((r[0] + r[1]) + (r[2] + r[3])) + ((r[4] + r[5]) + (r[6] + r[7]));
}
// exact max of 32 (order-independent, commutative -> any tree ok)
__device__ __forceinline__ float max32(const float* z) {
  float t16[16];
#pragma unroll
  for (int k = 0; k < 16; ++k) t16[k] = fmaxf(z[k], z[k + 16]);
  float t8[8];
#pragma unroll
  for (int k = 0; k < 8; ++k) t8[k] = fmaxf(t16[k], t16[k + 8]);
  float t4[4];
#pragma unroll
  for (int k = 0; k < 4; ++k) t4[k] = fmaxf(t8[k], t8[k + 4]);
  float t2a = fmaxf(t4[0], t4[2]), t2b = fmaxf(t4[1], t4[3]);
  return fmaxf(t2a, t2b);
}
// exact max of 8 (commutative -> exact)
__device__ __forceinline__ float max8(const float* z) {
  float t4[4];
#pragma unroll
  for (int k = 0; k < 4; ++k) t4[k] = fmaxf(z[k], z[k + 4]);
  return fmaxf(fmaxf(t4[0], t4[2]), fmaxf(t4[1], t4[3]));
}
// tree sum of 8 (reassociated sum is the R6-proven-safe class)
__device__ __forceinline__ float sum8(const float* e) {
  float t4[4];
#pragma unroll
  for (int k = 0; k < 4; ++k) t4[k] = e[k] + e[k + 4];
  return (t4[0] + t4[2]) + (t4[1] + t4[3]);
}

// ---------------- K4: forward/backward, 2 waves per chain ----------------
// R7 lesson: a single wave is ISSUE-bound (~82% busy on its SIMD — fusing a
// 2nd independent chain into the wave gave only 10% overlap). So the step's
// ops must land on MORE SIMDs: 2 waves per chain, wave w owns reduction
// indices i in [16w,16w+16); within a wave, quarter q=lane>>5 owns 8 of them.
// Per step each wave computes exact partial max m_w and partial sum
// S_w = sum exp(z - m_w) (8 exps/wave), exchanges (m_w,S_w) via LDS with ONE
// raw s_barrier (lgkmcnt-only wait — __syncthreads would drain vmcnt and
// serialize the lb prefetch), then both waves compute the identical combine:
//   m = fmax(m_w, m_o)                 -> BIT-EXACT np max
//   S = S_w0*exp(m_w0-m) + S_w1*exp(m_w1-m)   (canonical wave-0-first order)
//   a' = (logf(S) + m) + bcur          -> np-ordered big adds preserved
// Numerics: m_w - m is Sterbenz-exact; the rescale perturbs logS ~1e-6 —
// same safe class as the R6 sum-tree reorder (R1's failure axis — the
// big-magnitude adds and the exact max — is untouched).
__global__ __launch_bounds__(128, 1) __attribute__((amdgpu_waves_per_eu(1)))
void k_fb(const float* __restrict__ logA,
          const float* __restrict__ logpi,
          float* __restrict__ ws,
          float* __restrict__ out) {
  __shared__ float2 partsMS[2][2][2][32];   // [slot][wave][q][j] = (m_w, S_w)
  const float* lbg = ws + OFF_LB;
  float* bet = ws + OFF_BET;
  float* ev  = ws + OFF_EV;
  int chain = blockIdx.x;
  int b   = chain & 15;
  int dir = chain >> 4;
  int tid = threadIdx.x;
  int w   = tid >> 6;                    // wave 0/1: owns i in [16w,16w+16)
  int lane = tid & 63;
  int q = lane >> 5;                     // quarter: owns 8 of the wave's 16
  int j = lane & 31;
  int ib = (w << 4) + (q << 3);          // first reduction index of this lane
  const float* lb = lbg + (size_t)b * Tt * 32;

  if (dir == 0) {
    float ac[8];                         // A[ib+k][j]
#pragma unroll
    for (int k = 0; k < 8; ++k) {
      ac[k] = logA[(ib + k) * 32 + j];
      asm volatile("" : "+v"(ac[k]));
    }
    float* ao = out + (size_t)b * Tt * 32;
    float a = logpi[j] + lb[j];          // alpha[0], identical in both waves
    if (w == 0) ao[j] = a;
    float bA = lb[32 + j];
    float bB = lb[64 + j];
    float bC = lb[96 + j];
#pragma unroll 1
    for (int t = 1; t < Tt; ++t) {
      float bcur = bA; bA = bB; bB = bC;
      if (t + 3 < Tt) bC = lb[(size_t)(t + 3) * 32 + j];
      float sa[16];                      // this wave's 16 a_i -> SGPRs
#pragma unroll
      for (int k = 0; k < 16; ++k) sa[k] = rdlane(a, 16 * w + k);
      float z[8];
      if (q == 0) {
#pragma unroll
        for (int k = 0; k < 8; ++k) z[k] = sa[k] + ac[k];       // a_i + A[i][j]
      } else {
#pragma unroll
        for (int k = 0; k < 8; ++k) z[k] = sa[8 + k] + ac[k];
      }
      float mq = max8(z);
      float mlo, mhi; xhalf(mq, mlo, mhi);
      float mw = fmaxf(mlo, mhi);        // exact max over this wave's 16 i
      float e[8];
#pragma unroll
      for (int k = 0; k < 8; ++k) e[k] = __expf(z[k] - mw);     // Sterbenz-exact sub
      float sq = sum8(e);
      float slo, shi; xhalf(sq, slo, shi);
      float Sw = slo + shi;              // partial sum (local max)
      int p = t & 1;
      partsMS[p][w][q][j] = make_float2(mw, Sw);
      asm volatile("s_waitcnt lgkmcnt(0)" ::: "memory");
      __builtin_amdgcn_s_barrier();
      asm volatile("" ::: "memory");
      float2 oth = partsMS[p][w ^ 1][0][j];
      float mo = oth.x, So = oth.y;
      float m = fmaxf(mw, mo);           // bit-exact np max over all 32 i
      float m0 = (w == 0) ? mw : mo;     // canonical: wave-0 term first
      float S0 = (w == 0) ? Sw : So;
      float m1 = (w == 0) ? mo : mw;
      float S1 = (w == 0) ? So : Sw;
      float S = S0 * __expf(m0 - m) + S1 * __expf(m1 - m);
      a = (__logf(S) + m) + bcur;        // np-ordered big adds
      if (w == 0) ao[(size_t)t * 32 + j] = a;
    }
    // evidence = logsumexp(alpha[T-1]) — np-exact, identical to baseline
    if (w == 0) {
      float z[32];
#pragma unroll
      for (int i = 0; i < 32; ++i) z[i] = rdlane(a, i);
      float m = max32(z);
#pragma unroll
      for (int i = 0; i < 32; ++i) z[i] = __expf(z[i] - m);
      float S = npsum32(z);
      if (lane == 0) ev[b] = __logf(S) + m;
    }
  } else {
    float ar[8];                         // A[j][ib+k]
#pragma unroll
    for (int k = 0; k < 8; ++k) {
      ar[k] = logA[j * 32 + ib + k];
      asm volatile("" : "+v"(ar[k]));
    }
    float* bo = bet + (size_t)b * Tt * 32;
    if (w == 0) bo[(size_t)(Tt - 1) * 32 + j] = 0.f;
    float y = lb[(size_t)(Tt - 1) * 32 + j] + 0.f;   // logB[T-1] + beta[T-1]
    float bA = lb[(size_t)(Tt - 2) * 32 + j];
    float bB = lb[(size_t)(Tt - 3) * 32 + j];
    float bC = lb[(size_t)(Tt - 4) * 32 + j];
#pragma unroll 1
    for (int t = Tt - 2; t >= 0; --t) {
      float bcur = bA; bA = bB; bB = bC;
      if (t >= 3) bC = lb[(size_t)(t - 3) * 32 + j];
      float sy[16];                      // this wave's 16 y_i -> SGPRs
#pragma unroll
      for (int k = 0; k < 16; ++k) sy[k] = rdlane(y, 16 * w + k);
      float z[8];
      if (q == 0) {
#pragma unroll
        for (int k = 0; k < 8; ++k) z[k] = ar[k] + sy[k];       // A[j][i] + y_i
      } else {
#pragma unroll
        for (int k = 0; k < 8; ++k) z[k] = ar[k] + sy[8 + k];
      }
      float mq = max8(z);
      float mlo, mhi; xhalf(mq, mlo, mhi);
      float mw = fmaxf(mlo, mhi);
      float e[8];
#pragma unroll
      for (int k = 0; k < 8; ++k) e[k] = __expf(z[k] - mw);
      float sq = sum8(e);
      float slo, shi; xhalf(sq, slo, shi);
      float Sw = slo + shi;
      int p = t & 1;
      partsMS[p][w][q][j] = make_float2(mw, Sw);
      asm volatile("s_waitcnt lgkmcnt(0)" ::: "memory");
      __builtin_amdgcn_s_barrier();
      asm volatile("" ::: "memory");
      float2 oth = partsMS[p][w ^ 1][0][j];
      float mo = oth.x, So = oth.y;
      float m = fmaxf(mw, mo);
      float m0 = (w == 0) ? mw : mo;
      float S0 = (w == 0) ? Sw : So;
      float m1 = (w == 0) ? mo : mw;
      float S1 = (w == 0) ? So : Sw;
      float S = S0 * __expf(m0 - m) + S1 * __expf(m1 - m);
      float bv = __logf(S) + m;          // beta[t][j], identical in both waves
      if (w == 0) bo[(size_t)t * 32 + j] = bv;
      y = bcur + bv;                     // logB[t] + beta[t] for next step
    }
  }
}

// ---------------- K5: gamma = (alpha + beta) - evidence, fp32 ----------------
__global__ void k_gamma(const float* __restrict__ ws, float* __restrict__ out) {
  size_t idx = (size_t)blockIdx.x * blockDim.x + threadIdx.x;
  if (idx >= (size_t)NB * Tt * 32) return;
  int b = (int)(idx >> 17);            // T*S = 131072
  float a  = out[idx];
  float bb = ws[OFF_BET + idx];
  float e  = ws[OFF_EV + b];
  out[idx] = (a + bb) - e;
}

extern "C" void kernel_launch(void* const* d_in, const int* in_sizes, int n_in,
                              void* d_out, int out_size, void* d_ws, size_t ws_size,
                              hipStream_t stream) {
  const float* x     = (const float*)d_in[0];
  const float* means = (const float*)d_in[1];
  const float* covs  = (const float*)d_in[2];
  const float* logA  = (const float*)d_in[3];
  const float* logpi = (const float*)d_in[4];
  float* ws  = (float*)d_ws;
  float* out = (float*)d_out;

  k_chol<<<dim3(32), dim3(64), 0, stream>>>(covs, means, ws);
  k_emis<<<dim3(4096), dim3(64), 0, stream>>>(x, ws, ws + OFF_LB);
  k_fb<<<dim3(32), dim3(128), 0, stream>>>(logA, logpi, ws, out);
  k_gamma<<<dim3(8192), dim3(256), 0, stream>>>(ws, out);
}

// Round 10
// 2226.882 us; speedup vs baseline: 1.6175x; 1.2724x over previous
//
#include <hip/hip_runtime.h>
#include <math.h>

#define Tt 4096
#define NB 16

#define CLN2PI 1.8378770664093453f   // ln(2*pi)

// ws layout (float offsets)
#define OFF_W    0         // 131072  W = L^-1 per state (row-major, upper zeros)
#define OFF_D    131072    // 2048    d = W*mu
#define OFF_CST  133120    // 32      F*ln2pi + logdet  (nats)
#define OFF_EV   133152    // 16      evidence per batch (fp32 nats)
#define OFF_LB   133184    // 2097152 logB nats [b][t][s]
#define OFF_BET  2230336   // 2097152 beta  nats [b][t][s]
// total 4327488 floats = 17.3 MB

__device__ __forceinline__ float rdlane(float x, int l) {
  return __int_as_float(__builtin_amdgcn_readlane(__float_as_int(x), l));
}

// Per-lane cross-half exchange via v_permlane32_swap (VALU, ~10cy).
// With old=src=v: lo = v[lane&31], hi = v[32|(lane&31)] in ALL lanes.
// R4 lesson: inline-asm w/ two identical tied operands coalesces -> garbage;
// the intrinsic models both results -> safe. R5 lesson: rdlane(x, fixed_lane)
// only valid for wave-uniform x.
typedef unsigned int u32x2 __attribute__((ext_vector_type(2)));
__device__ __forceinline__ void xhalf(float v, float& lo, float& hi) {
  u32x2 r = __builtin_amdgcn_permlane32_swap(__float_as_uint(v), __float_as_uint(v),
                                             false, false);
  lo = __uint_as_float(r.x);
  hi = __uint_as_float(r.y);
}

// ---------------- K2: per-state Cholesky, W = L^-1, d = W*mu, cst ----------------
__global__ __launch_bounds__(64) void k_chol(const float* __restrict__ covs,
                                             const float* __restrict__ means,
                                             float* __restrict__ ws) {
  __shared__ float Am[64][65];
  __shared__ float Wl[64][65];
  int s = blockIdx.x, j = threadIdx.x;
  for (int r = 0; r < 64; ++r) {
    Am[r][j] = covs[((size_t)s * 64 + r) * 64 + j];
    Wl[r][j] = 0.f;
  }
  __syncthreads();
  for (int k = 0; k < 64; ++k) {
    float diag = sqrtf(Am[k][k]);
    float col = (j > k) ? Am[j][k] / diag : 0.f;
    __syncthreads();
    if (j == k) Am[k][k] = diag;
    if (j > k)  Am[j][k] = col;
    __syncthreads();
    if (j > k) {
      for (int g = k + 1; g <= j; ++g) Am[j][g] -= col * Am[g][k];
    }
    __syncthreads();
  }
  {
    int c = j;
    Wl[c][c] = 1.0f / Am[c][c];
    for (int f = c + 1; f < 64; ++f) {
      float ssum = 0.f;
      for (int g = c; g < f; ++g) ssum += Am[f][g] * Wl[g][c];
      Wl[f][c] = -ssum / Am[f][f];
    }
  }
  __syncthreads();
  for (int r = 0; r < 64; ++r)
    ws[OFF_W + ((size_t)s * 64 + r) * 64 + j] = Wl[r][j];
  {
    float acc = 0.f;
    for (int g = 0; g < 64; ++g) acc += Wl[j][g] * means[s * 64 + g];
    ws[OFF_D + s * 64 + j] = acc;
  }
  if (j == 0) {
    float logdet = 0.f;
    for (int k = 0; k < 64; ++k) logdet += __logf(Am[k][k]);
    logdet *= 2.0f;
    ws[OFF_CST + s] = 64.0f * CLN2PI + logdet;
  }
}

// ---------------- K3: emission logB (nats) ----------------
// R10: identical arithmetic (same fma order over g per f -> BIT-IDENTICAL
// logB), but W row chunks loaded as explicit float4s. The old per-element
// Ws[f*64+g] scalar loads (~16k loads/wave, 1 per fma) were ~2:1 load:fma
// issue — k_emis ran ~8x over its 55us compute floor. 4x dwordx4 per chunk
// cuts load instructions 4x and pipelines 4-deep.
__global__ __launch_bounds__(64) void k_emis(const float* __restrict__ x,
                                             const float* __restrict__ wsr,
                                             float* __restrict__ lb) {
  const float* W = wsr + OFF_W;
  const float* D = wsr + OFF_D;
  const float* C = wsr + OFF_CST;
  int bx = blockIdx.x;
  int sgrp = bx & 3;
  int pt = (bx >> 2) * 64 + threadIdx.x;
  const float* xr = x + (size_t)pt * 64;
  float xv[64];
#pragma unroll
  for (int c = 0; c < 16; ++c) {
    float4 q = ((const float4*)xr)[c];
    xv[4 * c + 0] = q.x; xv[4 * c + 1] = q.y;
    xv[4 * c + 2] = q.z; xv[4 * c + 3] = q.w;
  }
#pragma unroll 1
  for (int si = 0; si < 8; ++si) {
    int s = sgrp * 8 + si;
    const float* Ws = W + (size_t)s * 4096;
    const float* Ds = D + s * 64;
    float maha = 0.f;
#pragma unroll
    for (int f = 0; f < 64; ++f) {
      float z = -Ds[f];
#pragma unroll
      for (int ch = 0; ch < 4; ++ch) {
        if (ch <= (f >> 4)) {
          const float4* Wq = (const float4*)(Ws + f * 64 + ch * 16);
          float4 w0 = Wq[0], w1 = Wq[1], w2 = Wq[2], w3 = Wq[3];
          int g0 = ch * 16;
          z = fmaf(w0.x, xv[g0 +  0], z);
          z = fmaf(w0.y, xv[g0 +  1], z);
          z = fmaf(w0.z, xv[g0 +  2], z);
          z = fmaf(w0.w, xv[g0 +  3], z);
          z = fmaf(w1.x, xv[g0 +  4], z);
          z = fmaf(w1.y, xv[g0 +  5], z);
          z = fmaf(w1.z, xv[g0 +  6], z);
          z = fmaf(w1.w, xv[g0 +  7], z);
          z = fmaf(w2.x, xv[g0 +  8], z);
          z = fmaf(w2.y, xv[g0 +  9], z);
          z = fmaf(w2.z, xv[g0 + 10], z);
          z = fmaf(w2.w, xv[g0 + 11], z);
          z = fmaf(w3.x, xv[g0 + 12], z);
          z = fmaf(w3.y, xv[g0 + 13], z);
          z = fmaf(w3.z, xv[g0 + 14], z);
          z = fmaf(w3.w, xv[g0 + 15], z);
        }
      }
      maha = fmaf(z, z, maha);
    }
    lb[(size_t)pt * 32 + s] = -0.5f * (maha + C[s]);
  }
}

// np-pairwise-order sum of 32 (evidence only)
__device__ __forceinline__ float npsum32(const float* z) {
  float r[8];
#pragma unroll
  for (int k = 0; k < 8; ++k)
    r[k] = ((z[k] + z[k + 8]) + z[k + 16]) + z[k + 24];
  return ((r[0] + r[1]) + (r[2] + r[3])) + ((r[4] + r[5]) + (r[6] + r[7]));
}
// exact max of 32 (order-independent, commutative -> any tree ok)
__device__ __forceinline__ float max32(const float* z) {
  float t16[16];
#pragma unroll
  for (int k = 0; k < 16; ++k) t16[k] = fmaxf(z[k], z[k + 16]);
  float t8[8];
#pragma unroll
  for (int k = 0; k < 8; ++k) t8[k] = fmaxf(t16[k], t16[k + 8]);
  float t4[4];
#pragma unroll
  for (int k = 0; k < 4; ++k) t4[k] = fmaxf(t8[k], t8[k + 4]);
  float t2a = fmaxf(t4[0], t4[2]), t2b = fmaxf(t4[1], t4[3]);
  return fmaxf(t2a, t2b);
}
// exact max of 16 (commutative -> any tree yields THE max, bit-exact)
__device__ __forceinline__ float max16(const float* z) {
  float t8[8];
#pragma unroll
  for (int k = 0; k < 8; ++k) t8[k] = fmaxf(z[k], z[k + 8]);
  float t4[4];
#pragma unroll
  for (int k = 0; k < 4; ++k) t4[k] = fmaxf(t8[k], t8[k + 4]);
  return fmaxf(fmaxf(t4[0], t4[2]), fmaxf(t4[1], t4[3]));
}
// tree sum of 16 (reassociated small-magnitude sum: R6-proven safe class.
// R9 lesson closes the safe set: ONLY post-exp small-value reassociation and
// lane redistribution are allowed; all big-magnitude roundings (z-adds,
// logS+m, +bcur) and the exp inputs must replicate np bit-exactly.)
__device__ __forceinline__ float sum16(const float* e) {
  float t8[8];
#pragma unroll
  for (int k = 0; k < 8; ++k) t8[k] = e[k] + e[k + 8];
  float t4[4];
#pragma unroll
  for (int k = 0; k < 4; ++k) t4[k] = t8[k] + t8[k + 4];
  return (t4[0] + t4[2]) + (t4[1] + t4[3]);
}

// ---------------- K4: forward/backward, fp32 nats (R6, best verified) ----------------
// 1 wave per (batch, dir). Half-split: lane (h=lane>>5, j=lane&31) owns
// reduction indices i in [16h,16h+16) for state j -> 16 exps/step not 32.
// Structure locked by R7/R8/R9: one wave/chain (cross-wave sync costs more
// than it saves; fused chains don't overlap — SIMD ~80% issue-busy; exp
// factorization breaks np's big-add rounding walk).
__global__ __launch_bounds__(64, 1) __attribute__((amdgpu_waves_per_eu(1)))
void k_fb(const float* __restrict__ logA,
          const float* __restrict__ logpi,
          float* __restrict__ ws,
          float* __restrict__ out) {
  const float* lbg = ws + OFF_LB;
  float* bet = ws + OFF_BET;
  float* ev  = ws + OFF_EV;
  int chain = blockIdx.x;
  int b   = chain & 15;
  int dir = chain >> 4;
  int lane = threadIdx.x;
  int j = lane & 31;
  int h = lane >> 5;
  int i0 = h << 4;                       // first reduction index this half owns
  const float* lb = lbg + (size_t)b * Tt * 32;

  if (dir == 0) {
    float acol[16];                      // A[i0+k][j]
#pragma unroll
    for (int k = 0; k < 16; ++k) {
      acol[k] = logA[(i0 + k) * 32 + j];
      asm volatile("" : "+v"(acol[k]));
    }
    float* ao = out + (size_t)b * Tt * 32;
    float a = logpi[j] + lb[j];          // alpha[0], identical in both halves
    ao[j] = a;
    float bA = lb[32 + j];
    float bB = lb[64 + j];
    float bC = lb[96 + j];
#pragma unroll 1
    for (int t = 1; t < Tt; ++t) {
      float bcur = bA; bA = bB; bB = bC;
      if (t + 3 < Tt) bC = lb[(size_t)(t + 3) * 32 + j];
      float sa[32];                      // uniform (SGPR) gather of a-vector
#pragma unroll
      for (int i = 0; i < 32; ++i) sa[i] = rdlane(a, i);
      float z[16];
      if (h == 0) {
#pragma unroll
        for (int k = 0; k < 16; ++k) z[k] = sa[k] + acol[k];      // a_i + A[i][j]
      } else {
#pragma unroll
        for (int k = 0; k < 16; ++k) z[k] = sa[16 + k] + acol[k];
      }
      float mh = max16(z);               // per-(half,j) exact max
      float mlo, mhi;
      xhalf(mh, mlo, mhi);               // partner exchange (same j)
      float m = fmaxf(mlo, mhi);         // full max_i, same bits all lanes
      float e[16];
#pragma unroll
      for (int k = 0; k < 16; ++k) e[k] = __expf(z[k] - m);  // z-m exact
      float sh = sum16(e);               // per-(half,j) tree sum
      float slo, shi;
      xhalf(sh, slo, shi);
      float S = slo + shi;               // full sum, same bits all lanes
      a = (__logf(S) + m) + bcur;        // np-ordered final adds
      ao[(size_t)t * 32 + j] = a;        // halves write same value -> safe
    }
    // evidence = logsumexp(alpha[T-1]) — np-exact, identical to baseline
    float z[32];
#pragma unroll
    for (int i = 0; i < 32; ++i) z[i] = rdlane(a, i);
    float m = max32(z);
#pragma unroll
    for (int i = 0; i < 32; ++i) z[i] = __expf(z[i] - m);
    float S = npsum32(z);
    if (lane == 0) ev[b] = __logf(S) + m;
  } else {
    float arow[16];                      // A[j][i0+k]
#pragma unroll
    for (int k = 0; k < 16; ++k) {
      arow[k] = logA[j * 32 + i0 + k];
      asm volatile("" : "+v"(arow[k]));
    }
    float* bo = bet + (size_t)b * Tt * 32;
    bo[(size_t)(Tt - 1) * 32 + j] = 0.f;
    float y = lb[(size_t)(Tt - 1) * 32 + j] + 0.f;   // (logB[T-1] + beta[T-1])
    float bA = lb[(size_t)(Tt - 2) * 32 + j];
    float bB = lb[(size_t)(Tt - 3) * 32 + j];
    float bC = lb[(size_t)(Tt - 4) * 32 + j];
#pragma unroll 1
    for (int t = Tt - 2; t >= 0; --t) {
      float bcur = bA; bA = bB; bB = bC;
      if (t >= 3) bC = lb[(size_t)(t - 3) * 32 + j];
      float sy[32];                      // uniform (SGPR) gather of y-vector
#pragma unroll
      for (int i = 0; i < 32; ++i) sy[i] = rdlane(y, i);
      float z[16];
      if (h == 0) {
#pragma unroll
        for (int k = 0; k < 16; ++k) z[k] = arow[k] + sy[k];      // A[j][i]+y_i
      } else {
#pragma unroll
        for (int k = 0; k < 16; ++k) z[k] = arow[k] + sy[16 + k];
      }
      float mh = max16(z);
      float mlo, mhi;
      xhalf(mh, mlo, mhi);
      float m = fmaxf(mlo, mhi);
      float e[16];
#pragma unroll
      for (int k = 0; k < 16; ++k) e[k] = __expf(z[k] - m);
      float sh = sum16(e);
      float slo, shi;
      xhalf(sh, slo, shi);
      float S = slo + shi;
      float bv = __logf(S) + m;          // beta[t][j], same bits both halves
      bo[(size_t)t * 32 + j] = bv;
      y = bcur + bv;                     // (logB[t] + beta[t]) for next step
    }
  }
}

// ---------------- K5: gamma = (alpha + beta) - evidence, fp32 ----------------
__global__ void k_gamma(const float* __restrict__ ws, float* __restrict__ out) {
  size_t idx = (size_t)blockIdx.x * blockDim.x + threadIdx.x;
  if (idx >= (size_t)NB * Tt * 32) return;
  int b = (int)(idx >> 17);            // T*S = 131072
  float a  = out[idx];
  float bb = ws[OFF_BET + idx];
  float e  = ws[OFF_EV + b];
  out[idx] = (a + bb) - e;
}

extern "C" void kernel_launch(void* const* d_in, const int* in_sizes, int n_in,
                              void* d_out, int out_size, void* d_ws, size_t ws_size,
                              hipStream_t stream) {
  const float* x     = (const float*)d_in[0];
  const float* means = (const float*)d_in[1];
  const float* covs  = (const float*)d_in[2];
  const float* logA  = (const float*)d_in[3];
  const float* logpi = (const float*)d_in[4];
  float* ws  = (float*)d_ws;
  float* out = (float*)d_out;

  k_chol<<<dim3(32), dim3(64), 0, stream>>>(covs, means, ws);
  k_emis<<<dim3(4096), dim3(64), 0, stream>>>(x, ws, ws + OFF_LB);
  k_fb<<<dim3(32), dim3(64), 0, stream>>>(logA, logpi, ws, out);
  k_gamma<<<dim3(8192), dim3(256), 0, stream>>>(ws, out);
}